// Round 1
// baseline (580.830 us; speedup 1.0000x reference)
//
#include <hip/hip_runtime.h>
#include <hip/hip_bf16.h>
#include <math.h>

#define EMB_ATOM 256
#define EMB_EDGE 512
#define K_TOT    1024
#define BM       128
#define BN       128
#define BK       64

typedef __attribute__((ext_vector_type(8))) short bf16x8;
typedef __attribute__((ext_vector_type(4))) float f32x4;
typedef struct { unsigned short x, y, z, w; } us4;

static __device__ __forceinline__ unsigned short f2bf(float f) {
  union { float f; unsigned u; } x; x.f = f;
  unsigned r = x.u + 0x7fffu + ((x.u >> 16) & 1u);   // round-to-nearest-even
  return (unsigned short)(r >> 16);
}

static __device__ __forceinline__ void gload_lds16(const void* g, void* l) {
  __builtin_amdgcn_global_load_lds(
      (const __attribute__((address_space(1))) unsigned int*)g,
      (__attribute__((address_space(3))) unsigned int*)l, 16, 0, 0);
}

// ---- prep: W (1024x512 f32, k-major) -> Wt (512x1024 bf16, n-major) ----
__global__ __launch_bounds__(256) void cvt_wt_kernel(const float* __restrict__ W,
                                                     unsigned short* __restrict__ Wt) {
  int o = blockIdx.x * 256 + threadIdx.x;   // 512*1024 total
  int n = o >> 10, k = o & 1023;
  Wt[o] = f2bf(W[(size_t)k * EMB_EDGE + n]);
}

// ---- prep: h f32 -> bf16 ----
__global__ __launch_bounds__(256) void cvt_h_kernel(const float* __restrict__ h,
                                                    unsigned short* __restrict__ hb, int n4) {
  int i = blockIdx.x * 256 + threadIdx.x;
  if (i >= n4) return;
  const float4 v = ((const float4*)h)[i];
  us4 o; o.x = f2bf(v.x); o.y = f2bf(v.y); o.z = f2bf(v.z); o.w = f2bf(v.w);
  ((us4*)hb)[i] = o;
}

// ---- fused gather + GEMM + SiLU ----
__global__ __launch_bounds__(256) void gemm_gather_kernel(
    const unsigned short* __restrict__ hb,
    const float* __restrict__ m_ij,
    const int* __restrict__ idx_i,
    const int* __restrict__ idx_j,
    const unsigned short* __restrict__ Wt,
    float* __restrict__ out, int E)
{
  __shared__ unsigned short As[BM * BK];   // [128][64] row-major (e, k)
  __shared__ unsigned short Bs[BN * BK];   // [128][64] n-major   (n, k)

  const int bn   = blockIdx.x;             // 0..3  (fast-varying: L2/L3 reuse of m_ij)
  const int bm   = blockIdx.y;
  const int tid  = threadIdx.x;
  const int wave = tid >> 6;
  const int lane = tid & 63;
  const int row0 = bm * BM;

  // global_load_lds staging geometry: 64 lanes x 16B cover 8 rows of 64 bf16
  const int srow = lane >> 3;              // 0..7 row within 8-row group
  const int scol = (lane & 7) * 8;         // col in elements (16B chunks)

  // Hoist gather indices for this thread's 4 staging rows
  int arow[4], aii[4], ajj[4];
#pragma unroll
  for (int i = 0; i < 4; ++i) {
    int r = wave * 32 + i * 8 + srow;
    int e = row0 + r; if (e >= E) e = E - 1;
    arow[i] = r;
    aii[i] = idx_i[e];
    ajj[i] = idx_j[e];
  }

  const int wr = wave >> 1, wc = wave & 1; // wave's 64x64 quadrant
  const int fr = lane & 15;
  const int fq = lane >> 4;                // 0..3

  f32x4 acc[4][4];
#pragma unroll
  for (int m = 0; m < 4; ++m)
#pragma unroll
    for (int n = 0; n < 4; ++n) acc[m][n] = (f32x4)0.f;

  for (int kt = 0; kt < 16; ++kt) {
    __syncthreads();

    // ---- stage B tile: Bs[nl][kl] = Wt[bn*128+nl][kt*64+kl]
#pragma unroll
    for (int i = 0; i < 4; ++i) {
      int nl = wave * 32 + i * 8 + srow;
      const unsigned short* src = Wt + (size_t)(bn * BN + nl) * K_TOT + kt * BK + scol;
      gload_lds16(src, &Bs[nl * BK + scol]);
    }

    // ---- stage A tile
    if (kt < 8) {
      const int kh = (kt & 3) * BK;        // offset within the 256-wide h row
#pragma unroll
      for (int i = 0; i < 4; ++i) {
        int idx = (kt < 4) ? aii[i] : ajj[i];
        const unsigned short* src = hb + (size_t)idx * EMB_ATOM + kh + scol;
        gload_lds16(src, &As[arow[i] * BK + scol]);
      }
    } else {
      const int kk = (kt - 8) * BK;        // offset within the 512-wide m_ij row
#pragma unroll
      for (int it = 0; it < 8; ++it) {
        int flat = it * 1024 + tid * 4;    // 8192 f32 / 256 threads
        int r = flat >> 6, c = flat & 63;
        int e = row0 + r; if (e >= E) e = E - 1;
        const float4 v = *(const float4*)(m_ij + (size_t)e * EMB_EDGE + kk + c);
        us4 o; o.x = f2bf(v.x); o.y = f2bf(v.y); o.z = f2bf(v.z); o.w = f2bf(v.w);
        *(us4*)(&As[r * BK + c]) = o;
      }
    }

    __syncthreads();

    // ---- compute 64x64 quadrant: 2 k-sub-steps x 16 MFMA
#pragma unroll
    for (int ks = 0; ks < 2; ++ks) {
      bf16x8 a[4], b[4];
#pragma unroll
      for (int m = 0; m < 4; ++m)
        a[m] = *(const bf16x8*)(&As[(wr * 64 + m * 16 + fr) * BK + ks * 32 + fq * 8]);
#pragma unroll
      for (int n = 0; n < 4; ++n)
        b[n] = *(const bf16x8*)(&Bs[(wc * 64 + n * 16 + fr) * BK + ks * 32 + fq * 8]);
#pragma unroll
      for (int m = 0; m < 4; ++m)
#pragma unroll
        for (int n = 0; n < 4; ++n)
          acc[m][n] = __builtin_amdgcn_mfma_f32_16x16x32_bf16(a[m], b[n], acc[m][n], 0, 0, 0);
    }
  }

  // ---- epilogue: SiLU + store (C/D map: col = lane&15, row = (lane>>4)*4 + j)
#pragma unroll
  for (int m = 0; m < 4; ++m) {
    int er0 = row0 + wr * 64 + m * 16 + fq * 4;
#pragma unroll
    for (int n = 0; n < 4; ++n) {
      int col = bn * BN + wc * 64 + n * 16 + fr;
      f32x4 v = acc[m][n];
#pragma unroll
      for (int j = 0; j < 4; ++j) {
        int e = er0 + j;
        if (e < E) {
          float x = v[j];
          out[(size_t)e * EMB_EDGE + col] = x / (1.f + __expf(-x));
        }
      }
    }
  }
}

extern "C" void kernel_launch(void* const* d_in, const int* in_sizes, int n_in,
                              void* d_out, int out_size, void* d_ws, size_t ws_size,
                              hipStream_t stream) {
  const float* h    = (const float*)d_in[0];
  const float* m_ij = (const float*)d_in[1];
  const int*   ii   = (const int*)d_in[2];
  const int*   jj   = (const int*)d_in[3];
  const float* W    = (const float*)d_in[4];
  float* out = (float*)d_out;

  const int E   = in_sizes[2];
  const int hsz = in_sizes[0];           // N * 256

  unsigned short* Wt = (unsigned short*)d_ws;                       // 512*1024 bf16 = 1 MB
  unsigned short* hb = (unsigned short*)d_ws + (size_t)512 * 1024;  // hsz bf16 = 25.6 MB

  cvt_wt_kernel<<<(512 * 1024) / 256, 256, 0, stream>>>(W, Wt);
  cvt_h_kernel<<<(hsz / 4 + 255) / 256, 256, 0, stream>>>(h, hb, hsz / 4);

  dim3 grid(EMB_EDGE / BN, (E + BM - 1) / BM);
  gemm_gather_kernel<<<grid, 256, 0, stream>>>(hb, m_ij, ii, jj, Wt, out, E);
}

// Round 2
// 580.022 us; speedup vs baseline: 1.0014x; 1.0014x over previous
//
#include <hip/hip_runtime.h>
#include <hip/hip_bf16.h>
#include <math.h>

#define EMB_ATOM 256
#define EMB_EDGE 512
#define K_TOT    1024

typedef __attribute__((ext_vector_type(8))) short bf16x8;
typedef __attribute__((ext_vector_type(4))) float f32x4;
typedef struct { unsigned short x, y, z, w; } us4;

static __device__ __forceinline__ unsigned short f2bf(float f) {
  union { float f; unsigned u; } x; x.f = f;
  unsigned r = x.u + 0x7fffu + ((x.u >> 16) & 1u);   // RTNE
  return (unsigned short)(r >> 16);
}
static __device__ __forceinline__ float bf2f(unsigned short b) {
  union { unsigned u; float f; } x; x.u = ((unsigned)b) << 16; return x.f;
}
static __device__ __forceinline__ us4 f4bf(float4 v) {
  us4 o; o.x = f2bf(v.x); o.y = f2bf(v.y); o.z = f2bf(v.z); o.w = f2bf(v.w); return o;
}
static __device__ __forceinline__ void gload_lds16(const void* g, void* l) {
  __builtin_amdgcn_global_load_lds(
      (const __attribute__((address_space(1))) unsigned int*)g,
      (__attribute__((address_space(3))) unsigned int*)l, 16, 0, 0);
}
static __device__ __forceinline__ float silu_f(float x) { return x / (1.f + __expf(-x)); }

// ---------------- prep kernels ----------------
__global__ __launch_bounds__(256) void cvt_h_kernel(const float* __restrict__ h,
                                                    unsigned short* __restrict__ hb, int n4) {
  int i = blockIdx.x * 256 + threadIdx.x;
  if (i >= n4) return;
  const float4 v = ((const float4*)h)[i];
  ((us4*)hb)[i] = f4bf(v);
}

// Wt_h: (1024 c, 256 k) bf16, c-major.  c<512: W[k][c]; c>=512: W[256+k][c-512]
__global__ __launch_bounds__(256) void cvt_wh_kernel(const float* __restrict__ W,
                                                     unsigned short* __restrict__ Wt_h) {
  int o = blockIdx.x * 256 + threadIdx.x;    // 1024*256
  int c = o >> 8, k = o & 255;
  float v = (c < 512) ? W[(size_t)k * EMB_EDGE + c]
                      : W[(size_t)(256 + k) * EMB_EDGE + (c - 512)];
  Wt_h[o] = f2bf(v);
}

// Wt_m: (512 c, 512 k) bf16, c-major.  Wt_m[c][k] = W[512+k][c]
__global__ __launch_bounds__(256) void cvt_wm_kernel(const float* __restrict__ W,
                                                     unsigned short* __restrict__ Wt_m) {
  int o = blockIdx.x * 256 + threadIdx.x;    // 512*512
  int c = o >> 9, k = o & 511;
  Wt_m[o] = f2bf(W[(size_t)(512 + k) * EMB_EDGE + c]);
}

// ---------------- H-GEMM: H12 = hb @ [W1|W2]  (N x 1024, bf16) ----------------
__global__ __launch_bounds__(256) void hgemm_kernel(
    const unsigned short* __restrict__ hb,     // (N,256)
    const unsigned short* __restrict__ Wt_h,   // (1024,256) c-major
    unsigned short* __restrict__ H12, int N)
{
  __shared__ unsigned short As[2][128 * 64];
  __shared__ unsigned short Bs[2][128 * 64];
  const int bn = blockIdx.x;       // 0..7
  const int bm = blockIdx.y;
  const int row0 = bm * 128;
  const int tid = threadIdx.x, wave = tid >> 6, lane = tid & 63;
  const int srow = lane >> 3;
  const int schunk = ((lane & 7) ^ srow) * 8;  // pre-swizzled source chunk (elems)

  size_t abase[4]; size_t bbase[4];
#pragma unroll
  for (int i = 0; i < 4; ++i) {
    int r = wave * 32 + i * 8 + srow;
    int e = row0 + r; if (e >= N) e = N - 1;
    abase[i] = (size_t)e * EMB_ATOM;
    bbase[i] = (size_t)(bn * 128 + r) * EMB_ATOM;
  }

  const int wr = wave >> 1, wc = wave & 1, fr = lane & 15, fq = lane >> 4;
  const int fs = fr & 7;

  f32x4 acc[4][4];
#pragma unroll
  for (int m = 0; m < 4; ++m)
#pragma unroll
    for (int n = 0; n < 4; ++n) acc[m][n] = (f32x4)0.f;

  // prologue: stage kt=0
#pragma unroll
  for (int i = 0; i < 4; ++i) {
    gload_lds16(hb + abase[i] + schunk,   &As[0][(wave * 32 + i * 8) * 64 + lane * 8]);
    gload_lds16(Wt_h + bbase[i] + schunk, &Bs[0][(wave * 32 + i * 8) * 64 + lane * 8]);
  }
  __syncthreads();

  int cur = 0;
  for (int kt = 0; kt < 4; ++kt) {
    int nxt = cur ^ 1;
    if (kt < 3) {
      int kk = (kt + 1) * 64;
#pragma unroll
      for (int i = 0; i < 4; ++i) {
        gload_lds16(hb + abase[i] + kk + schunk,   &As[nxt][(wave * 32 + i * 8) * 64 + lane * 8]);
        gload_lds16(Wt_h + bbase[i] + kk + schunk, &Bs[nxt][(wave * 32 + i * 8) * 64 + lane * 8]);
      }
    }
#pragma unroll
    for (int ks = 0; ks < 2; ++ks) {
      bf16x8 a[4], b[4];
#pragma unroll
      for (int m = 0; m < 4; ++m)
        a[m] = *(const bf16x8*)(&As[cur][(wr * 64 + m * 16 + fr) * 64 + (((ks * 4 + fq) ^ fs) << 3)]);
#pragma unroll
      for (int n = 0; n < 4; ++n)
        b[n] = *(const bf16x8*)(&Bs[cur][(wc * 64 + n * 16 + fr) * 64 + (((ks * 4 + fq) ^ fs) << 3)]);
#pragma unroll
      for (int m = 0; m < 4; ++m)
#pragma unroll
        for (int n = 0; n < 4; ++n)
          acc[m][n] = __builtin_amdgcn_mfma_f32_16x16x32_bf16(a[m], b[n], acc[m][n], 0, 0, 0);
    }
    __syncthreads();
    cur = nxt;
  }

#pragma unroll
  for (int m = 0; m < 4; ++m) {
    int er0 = row0 + wr * 64 + m * 16 + fq * 4;
#pragma unroll
    for (int n = 0; n < 4; ++n) {
      int col = bn * 128 + wc * 64 + n * 16 + fr;
      f32x4 v = acc[m][n];
#pragma unroll
      for (int j = 0; j < 4; ++j) {
        int e = er0 + j;
        if (e < N) H12[(size_t)e * 1024 + col] = f2bf(v[j]);
      }
    }
  }
}

// ---------------- main GEMM: out = SiLU(m_ij @ W3 + H12[i] + H12[j]) ----------------
__global__ __launch_bounds__(256) void mgemm_kernel(
    const float* __restrict__ m_ij,
    const int* __restrict__ idx_i,
    const int* __restrict__ idx_j,
    const unsigned short* __restrict__ Wt_m,   // (512,512) c-major
    const unsigned short* __restrict__ H12,    // (N,1024)
    float* __restrict__ out, int E, int nbm)
{
  __shared__ unsigned short As[2][128 * 64];
  __shared__ unsigned short Bs[2][128 * 64];

  // XCD-pairing map: blocks with same bm land on the same XCD (id % 8 == bm % 8)
  int b  = blockIdx.x;
  int bm = (b >> 5) * 8 + (b & 7);
  int bn = (b >> 3) & 3;
  if (bm >= nbm) return;
  const int row0 = bm * 128;
  const int tid = threadIdx.x, wave = tid >> 6, lane = tid & 63;
  const int srow = lane >> 3;
  const int schunk = ((lane & 7) ^ srow) * 8;

  size_t bbase[4];
#pragma unroll
  for (int i = 0; i < 4; ++i)
    bbase[i] = (size_t)(bn * 128 + wave * 32 + i * 8 + srow) * 512;

  // A reg-staging geometry: per it, thread loads float4 at (row=it*16+arow_t, col=acol)
  const int arow_t = tid >> 4;               // 0..15
  const int acol   = (tid & 15) * 4;         // 0..60
  const int asw    = (((acol >> 3) ^ (arow_t & 7)) << 3) | (acol & 7);  // swizzled col
  const float* aptr[8];
#pragma unroll
  for (int it = 0; it < 8; ++it) {
    int e = row0 + it * 16 + arow_t; if (e >= E) e = E - 1;
    aptr[it] = m_ij + (size_t)e * EMB_EDGE + acol;
  }

  const int wr = wave >> 1, wc = wave & 1, fr = lane & 15, fq = lane >> 4;
  const int fs = fr & 7;

  f32x4 acc[4][4];
#pragma unroll
  for (int m = 0; m < 4; ++m)
#pragma unroll
    for (int n = 0; n < 4; ++n) acc[m][n] = (f32x4)0.f;

  // prologue: stage kt=0 into buf0
  {
    float4 r[8];
#pragma unroll
    for (int it = 0; it < 8; ++it) r[it] = *(const float4*)(aptr[it]);
#pragma unroll
    for (int i = 0; i < 4; ++i)
      gload_lds16(Wt_m + bbase[i] + schunk, &Bs[0][(wave * 32 + i * 8) * 64 + lane * 8]);
#pragma unroll
    for (int it = 0; it < 8; ++it)
      *(us4*)(&As[0][(it * 16 + arow_t) * 64 + asw]) = f4bf(r[it]);
    __syncthreads();
  }

  int cur = 0;
  for (int kt = 0; kt < 8; ++kt) {
    int nxt = cur ^ 1;
    float4 r[8];
    const bool pre = (kt < 7);
    if (pre) {
      int kk = (kt + 1) * 64;
#pragma unroll
      for (int it = 0; it < 8; ++it) r[it] = *(const float4*)(aptr[it] + kk);
#pragma unroll
      for (int i = 0; i < 4; ++i)
        gload_lds16(Wt_m + bbase[i] + kk + schunk, &Bs[nxt][(wave * 32 + i * 8) * 64 + lane * 8]);
    }
#pragma unroll
    for (int ks = 0; ks < 2; ++ks) {
      bf16x8 a[4], bb[4];
#pragma unroll
      for (int m = 0; m < 4; ++m)
        a[m] = *(const bf16x8*)(&As[cur][(wr * 64 + m * 16 + fr) * 64 + (((ks * 4 + fq) ^ fs) << 3)]);
#pragma unroll
      for (int n = 0; n < 4; ++n)
        bb[n] = *(const bf16x8*)(&Bs[cur][(wc * 64 + n * 16 + fr) * 64 + (((ks * 4 + fq) ^ fs) << 3)]);
#pragma unroll
      for (int m = 0; m < 4; ++m)
#pragma unroll
        for (int n = 0; n < 4; ++n)
          acc[m][n] = __builtin_amdgcn_mfma_f32_16x16x32_bf16(a[m], bb[n], acc[m][n], 0, 0, 0);
    }
    if (pre) {
#pragma unroll
      for (int it = 0; it < 8; ++it)
        *(us4*)(&As[nxt][(it * 16 + arow_t) * 64 + asw]) = f4bf(r[it]);
    }
    __syncthreads();
    cur = nxt;
  }

  // epilogue: gather H12 + SiLU + store
#pragma unroll
  for (int m = 0; m < 4; ++m) {
#pragma unroll
    for (int j = 0; j < 4; ++j) {
      int e = row0 + wr * 64 + m * 16 + fq * 4 + j;
      if (e < E) {
        size_t gi = (size_t)idx_i[e] * 1024;
        size_t gj = (size_t)idx_j[e] * 1024 + 512;
#pragma unroll
        for (int n = 0; n < 4; ++n) {
          int col = bn * 128 + wc * 64 + n * 16 + fr;
          float x = acc[m][n][j] + bf2f(H12[gi + col]) + bf2f(H12[gj + col]);
          out[(size_t)e * EMB_EDGE + col] = silu_f(x);
        }
      }
    }
  }
}

// ---------------- fallback (round-1 fused path, needs only ~27 MB ws) ----------------
__global__ __launch_bounds__(256) void cvt_wt_kernel(const float* __restrict__ W,
                                                     unsigned short* __restrict__ Wt) {
  int o = blockIdx.x * 256 + threadIdx.x;
  int n = o >> 10, k = o & 1023;
  Wt[o] = f2bf(W[(size_t)k * EMB_EDGE + n]);
}

__global__ __launch_bounds__(256) void gemm_gather_kernel(
    const unsigned short* __restrict__ hb,
    const float* __restrict__ m_ij,
    const int* __restrict__ idx_i,
    const int* __restrict__ idx_j,
    const unsigned short* __restrict__ Wt,
    float* __restrict__ out, int E)
{
  __shared__ unsigned short As[128 * 64];
  __shared__ unsigned short Bs[128 * 64];
  const int bn = blockIdx.x, bm = blockIdx.y;
  const int tid = threadIdx.x, wave = tid >> 6, lane = tid & 63;
  const int row0 = bm * 128;
  const int srow = lane >> 3, scol = (lane & 7) * 8;
  int arow[4], aii[4], ajj[4];
#pragma unroll
  for (int i = 0; i < 4; ++i) {
    int r = wave * 32 + i * 8 + srow;
    int e = row0 + r; if (e >= E) e = E - 1;
    arow[i] = r; aii[i] = idx_i[e]; ajj[i] = idx_j[e];
  }
  const int wr = wave >> 1, wc = wave & 1, fr = lane & 15, fq = lane >> 4;
  f32x4 acc[4][4];
#pragma unroll
  for (int m = 0; m < 4; ++m)
#pragma unroll
    for (int n = 0; n < 4; ++n) acc[m][n] = (f32x4)0.f;
  for (int kt = 0; kt < 16; ++kt) {
    __syncthreads();
#pragma unroll
    for (int i = 0; i < 4; ++i) {
      int nl = wave * 32 + i * 8 + srow;
      gload_lds16(Wt + (size_t)(bn * 128 + nl) * K_TOT + kt * 64 + scol, &Bs[nl * 64 + scol]);
    }
    if (kt < 8) {
      const int kh = (kt & 3) * 64;
#pragma unroll
      for (int i = 0; i < 4; ++i) {
        int idx = (kt < 4) ? aii[i] : ajj[i];
        gload_lds16(hb + (size_t)idx * EMB_ATOM + kh + scol, &As[arow[i] * 64 + scol]);
      }
    } else {
      const int kk = (kt - 8) * 64;
#pragma unroll
      for (int it = 0; it < 8; ++it) {
        int flat = it * 1024 + tid * 4;
        int r = flat >> 6, c = flat & 63;
        int e = row0 + r; if (e >= E) e = E - 1;
        const float4 v = *(const float4*)(m_ij + (size_t)e * EMB_EDGE + kk + c);
        *(us4*)(&As[r * 64 + c]) = f4bf(v);
      }
    }
    __syncthreads();
#pragma unroll
    for (int ks = 0; ks < 2; ++ks) {
      bf16x8 a[4], b[4];
#pragma unroll
      for (int m = 0; m < 4; ++m)
        a[m] = *(const bf16x8*)(&As[(wr * 64 + m * 16 + fr) * 64 + ks * 32 + fq * 8]);
#pragma unroll
      for (int n = 0; n < 4; ++n)
        b[n] = *(const bf16x8*)(&Bs[(wc * 64 + n * 16 + fr) * 64 + ks * 32 + fq * 8]);
#pragma unroll
      for (int m = 0; m < 4; ++m)
#pragma unroll
        for (int n = 0; n < 4; ++n)
          acc[m][n] = __builtin_amdgcn_mfma_f32_16x16x32_bf16(a[m], b[n], acc[m][n], 0, 0, 0);
    }
  }
#pragma unroll
  for (int m = 0; m < 4; ++m) {
    int er0 = row0 + wr * 64 + m * 16 + fq * 4;
#pragma unroll
    for (int n = 0; n < 4; ++n) {
      int col = bn * 128 + wc * 64 + n * 16 + fr;
      f32x4 v = acc[m][n];
#pragma unroll
      for (int j = 0; j < 4; ++j) {
        int e = er0 + j;
        if (e < E) out[(size_t)e * EMB_EDGE + col] = silu_f(v[j]);
      }
    }
  }
}

extern "C" void kernel_launch(void* const* d_in, const int* in_sizes, int n_in,
                              void* d_out, int out_size, void* d_ws, size_t ws_size,
                              hipStream_t stream) {
  const float* h    = (const float*)d_in[0];
  const float* m_ij = (const float*)d_in[1];
  const int*   ii   = (const int*)d_in[2];
  const int*   jj   = (const int*)d_in[3];
  const float* W    = (const float*)d_in[4];
  float* out = (float*)d_out;

  const int hsz = in_sizes[0];
  const int N   = hsz / EMB_ATOM;
  const int E   = in_sizes[2];

  unsigned short* hb   = (unsigned short*)d_ws;              // hsz
  unsigned short* Wt_h = hb + hsz;                           // 1024*256
  unsigned short* Wt_m = Wt_h + 1024 * 256;                  // 512*512
  unsigned short* H12  = Wt_m + 512 * 512;                   // N*1024
  size_t need = ((size_t)hsz + 1024 * 256 + 512 * 512 + (size_t)N * 1024) * 2;

  if (ws_size >= need) {
    cvt_h_kernel<<<(hsz / 4 + 255) / 256, 256, 0, stream>>>(h, hb, hsz / 4);
    cvt_wh_kernel<<<1024, 256, 0, stream>>>(W, Wt_h);
    cvt_wm_kernel<<<1024, 256, 0, stream>>>(W, Wt_m);
    int nbmh = (N + 127) / 128;
    hgemm_kernel<<<dim3(8, nbmh), 256, 0, stream>>>(hb, Wt_h, H12, N);
    int nbm  = (E + 127) / 128;
    int ngrp = (nbm + 7) / 8;
    mgemm_kernel<<<ngrp * 32, 256, 0, stream>>>(m_ij, ii, jj, Wt_m, H12, out, E, nbm);
  } else {
    unsigned short* Wt  = (unsigned short*)d_ws;             // 512*1024
    unsigned short* hbf = Wt + 512 * 1024;                   // hsz
    cvt_wt_kernel<<<(512 * 1024) / 256, 256, 0, stream>>>(W, Wt);
    cvt_h_kernel<<<(hsz / 4 + 255) / 256, 256, 0, stream>>>(h, hbf, hsz / 4);
    dim3 grid(4, (E + 127) / 128);
    gemm_gather_kernel<<<grid, 256, 0, stream>>>(hbf, m_ij, ii, jj, Wt, out, E);
  }
}